// Round 9
// baseline (330.189 us; speedup 1.0000x reference)
//
#include <hip/hip_runtime.h>

// ---- problem constants ----
constexpr int B_  = 128;
constexpr int T_  = 24;
constexpr int E_  = 512;
constexpr int H_  = 512;
constexpr int V_  = 10000;
constexpr int G4  = 2048;   // 4*H
constexpr int TP1 = 25;     // T+1

typedef __attribute__((ext_vector_type(8))) short bf16x8;   // 8 bf16 = 4 VGPR
typedef __attribute__((ext_vector_type(4))) short short4v;  // 4 bf16 = 8 B
typedef __attribute__((ext_vector_type(4))) float f32x4;

#define MFMA_16x16x32_BF16(a, b, c) __builtin_amdgcn_mfma_f32_16x16x32_bf16((a), (b), (c), 0, 0, 0)

// fp32 -> bf16 round-to-nearest-even (bit-level, no header ABI dependence)
__device__ inline unsigned short f2bf(float f) {
    unsigned int u = __float_as_uint(f);
    unsigned int r = (u + 0x7FFFu + ((u >> 16) & 1u)) >> 16;
    return (unsigned short)r;
}

// async global->LDS, 16B per lane. LDS dest must be linear-in-lane.
__device__ inline void gl16(const unsigned short* g, unsigned short* l) {
    __builtin_amdgcn_global_load_lds(
        (const __attribute__((address_space(1))) unsigned int*)g,
        (__attribute__((address_space(3))) unsigned int*)l, 16, 0, 0);
}

// LDS granule swizzle for [R][32] bf16 tiles (4 granules of 16B per row).
// Stored granule s = ((row<<2)|lq) ^ (row&7)  (bijective; 16-row fragment
// reads hit each bank-quad exactly twice = free). Reader:
__device__ inline int swz16(int row, int lq) {      // returns short offset
    return (((row << 2) | lq) ^ (row & 7)) << 3;
}
// Writer inverse: thread i stages stored granule i of each 512-granule
// (128-row) chunk; logical granule li = i ^ m, m = ((i>>2)&7) ^ ((i>>4)&1).

// ---------------------------------------------------------------------------
// ALL prep in ONE launch: fp32->bf16 weight staging, embedding gather,
// t=0 one-hot row + length tail (when do_start), per-producer flag reset.
// Segment sizes are exact multiples of 256 threads -> no bounds checks.
// ---------------------------------------------------------------------------
__global__ __launch_bounds__(256) void k_prep(const float* __restrict__ Wih,
                                              const float* __restrict__ Whh,
                                              const float* __restrict__ Wout,
                                              const float* __restrict__ images,
                                              const float* __restrict__ Wemb,
                                              const int* __restrict__ captions,
                                              const int* __restrict__ cap_len,
                                              unsigned short* __restrict__ dWih,
                                              unsigned short* __restrict__ dWhh,
                                              unsigned short* __restrict__ dWout,
                                              unsigned short* __restrict__ dimg,
                                              unsigned short* __restrict__ Xemb,
                                              float* __restrict__ out,
                                              unsigned* __restrict__ flg,
                                              int do_start) {
    int b = blockIdx.x;
    if (b == 0) flg[threadIdx.x * 32] = 0u;      // 256 producer flags
    if (b < 7112) {                              // fp32 -> bf16 segments
        const float* src; unsigned short* dst; int i;
        if (b < 1024)      { src = Wih;    dst = dWih;  i = b * 256 + threadIdx.x; }
        else if (b < 2048) { src = Whh;    dst = dWhh;  i = (b - 1024) * 256 + threadIdx.x; }
        else if (b < 7048) { src = Wout;   dst = dWout; i = (b - 2048) * 256 + threadIdx.x; }
        else               { src = images; dst = dimg;  i = (b - 7048) * 256 + threadIdx.x; }
        float4 v = ((const float4*)src)[i];
        short4v o;
        o[0] = (short)f2bf(v.x); o[1] = (short)f2bf(v.y);
        o[2] = (short)f2bf(v.z); o[3] = (short)f2bf(v.w);
        ((short4v*)dst)[i] = o;
    } else if (b < 8648) {                       // embedding gather
        int i = (b - 7112) * 256 + threadIdx.x;  // < 393216
        int row = i >> 7;                        // m = t*128 + bb
        int k4  = i & 127;
        int bb = row & 127, t = row >> 7;
        int tok = captions[bb * T_ + t];
        short4v o = {0, 0, 0, 0};
        if (tok > 0 && tok < V_) {               // tok==0 is padding -> zeros
            float4 v = ((const float4*)(Wemb + (long)tok * E_))[k4];
            o[0] = (short)f2bf(v.x); o[1] = (short)f2bf(v.y);
            o[2] = (short)f2bf(v.z); o[3] = (short)f2bf(v.w);
        }
        ((short4v*)Xemb)[(long)row * 128 + k4] = o;
    } else if (do_start) {                       // t=0 one-hot row + tail
        int idx = (b - 8648) * 256 + threadIdx.x;
        constexpr int Q = V_ / 4;                // 2500 float4 per row
        if (idx < B_ * Q) {
            int bb = idx / Q;
            int q = idx - bb * Q;
            float4 zero = {0.f, 0.f, 0.f, 0.f};
            float4 one1 = {0.f, 1.f, 0.f, 0.f};  // one-hot at v=1
            ((float4*)out)[(long)bb * (TP1 * Q) + q] = (q == 0) ? one1 : zero;
        }
        if (idx < B_)
            out[(size_t)B_ * TP1 * V_ + idx] = (float)(cap_len[idx] - 1);
    }
}

// late k_start for the (unused in practice) !ws_ok fallback
__global__ __launch_bounds__(256) void k_start(float* __restrict__ out,
                                               const int* __restrict__ cap_len) {
    int idx = blockIdx.x * 256 + threadIdx.x;
    constexpr int Q = V_ / 4;
    if (idx < B_ * Q) {
        int b = idx / Q;
        int q = idx - b * Q;
        float4 zero = {0.f, 0.f, 0.f, 0.f};
        float4 one1 = {0.f, 1.f, 0.f, 0.f};
        ((float4*)out)[(long)b * (TP1 * Q) + q] = (q == 0) ? one1 : zero;
    }
    if (idx < B_) out[(size_t)B_ * TP1 * V_ + idx] = (float)(cap_len[idx] - 1);
}

// ---------------------------------------------------------------------------
// P[m][n] = Xemb[m].Wih[n] + bih[n] + bhh[n]  (fp32). M=3072, N=2048, K=512.
// 128x128 LDS-staged tiles, XCD-swizzled. (Unchanged — passing.)
// ---------------------------------------------------------------------------
__global__ __launch_bounds__(256) void k_pregemm(const unsigned short* __restrict__ Xemb,
                                                 const unsigned short* __restrict__ Wih,
                                                 const float* __restrict__ bih,
                                                 const float* __restrict__ bhh,
                                                 float* __restrict__ P) {
    __shared__ unsigned short ldsA[2][4096];     // [buf][128*32] swizzled
    __shared__ unsigned short ldsB[2][4096];
    int bid = blockIdx.x;
    int xcd = bid & 7;
    int q   = bid >> 3;                          // 0..47
    int MI  = xcd * 3 + (q % 3);                 // 0..23
    int NI  = q / 3;                             // 0..15
    int i    = threadIdx.x;
    int w = i >> 6, lane = i & 63;
    int lm = lane & 15, lq = lane >> 4;
    int wr = w >> 1, wc = w & 1;

    int mm0 = ((i >> 2) & 7) ^ ((i >> 4) & 1);   // writer inverse swizzle
    int li  = i ^ mm0;
    const unsigned short* gA = Xemb + (size_t)(MI * 128 + (li >> 2)) * 512 + (li & 3) * 8;
    const unsigned short* gB = Wih  + (size_t)(NI * 128 + (li >> 2)) * 512 + (li & 3) * 8;
    unsigned short* lA = &ldsA[0][0] + i * 8;
    unsigned short* lB = &ldsB[0][0] + i * 8;

    auto stage = [&](int buf, int ks) {
        int go = ks * 32;
        gl16(gA + go,            lA + buf * 4096);
        gl16(gA + go + 64 * 512, lA + buf * 4096 + 2048);
        gl16(gB + go,            lB + buf * 4096);
        gl16(gB + go + 64 * 512, lB + buf * 4096 + 2048);
    };

    f32x4 acc[4][4] = {};
    stage(0, 0);
    for (int ksi = 0; ksi < 16; ksi++) {
        int cur = ksi & 1;
        if (ksi < 15) stage(cur ^ 1, ksi + 1);
        __syncthreads();
        bf16x8 af[4], bfr[4];
        #pragma unroll
        for (int mi = 0; mi < 4; mi++)
            af[mi] = *(const bf16x8*)&ldsA[cur][swz16(wr * 64 + mi * 16 + lm, lq)];
        #pragma unroll
        for (int ni = 0; ni < 4; ni++)
            bfr[ni] = *(const bf16x8*)&ldsB[cur][swz16(wc * 64 + ni * 16 + lm, lq)];
        #pragma unroll
        for (int mi = 0; mi < 4; mi++)
            #pragma unroll
            for (int ni = 0; ni < 4; ni++)
                acc[mi][ni] = MFMA_16x16x32_BF16(af[mi], bfr[ni], acc[mi][ni]);
        __syncthreads();
    }

    float bias[4];
    #pragma unroll
    for (int ni = 0; ni < 4; ni++) {
        int n = NI * 128 + wc * 64 + ni * 16 + lm;
        bias[ni] = bih[n] + bhh[n];
    }
    #pragma unroll
    for (int mi = 0; mi < 4; mi++) {
        #pragma unroll
        for (int r = 0; r < 4; r++) {
            int m = MI * 128 + wr * 64 + mi * 16 + lq * 4 + r;
            #pragma unroll
            for (int ni = 0; ni < 4; ni++) {
                int n = NI * 128 + wc * 64 + ni * 16 + lm;
                P[(size_t)m * G4 + n] = acc[mi][ni][r] + bias[ni];
            }
        }
    }
}

// ---------------------------------------------------------------------------
// Persistent LSTM recurrence, per-producer flags. R8 structure with one
// change: Hall store moved AFTER the flag signal — it is only consumed after
// kernel end, so its write-ack no longer sits inside the per-step vmcnt(0)
// drain on the critical path.
// ---------------------------------------------------------------------------
__global__ __launch_bounds__(256, 1) void k_lstm(const float* __restrict__ P,
                                                 const unsigned short* __restrict__ h0,
                                                 unsigned* __restrict__ hx0,
                                                 unsigned* __restrict__ hx1,
                                                 unsigned short* __restrict__ Hall,
                                                 const unsigned short* __restrict__ Whh,
                                                 unsigned* __restrict__ flg) {
    __shared__ float part[16][4][64];            // [g*4+r][wave][lane]
    int w    = threadIdx.x >> 6;                 // 0..3 (K-slice / cell row)
    int lane = threadIdx.x & 63;
    int lm = lane & 15, lq = lane >> 4;
    int MI = blockIdx.x >> 5;                    // 0..7
    int HG = blockIdx.x & 31;                    // 0..31
    int hcol = HG * 16 + lm;
    int ks = w * 128;
    int brow = MI * 16 + lq * 4 + w;             // this lane's cell row (b)
    unsigned* myFlg = flg + (MI * 32 + HG) * 32;          // producer flag
    unsigned* wFlg  = flg + (MI * 32 + (w << 3)) * 32;    // octet-w flag base

    // resident Whh fragments (bf16), reused all 24 steps
    bf16x8 bw[4][4];                             // [gate][kk]
    #pragma unroll
    for (int g = 0; g < 4; g++)
        #pragma unroll
        for (int kk = 0; kk < 4; kk++)
            bw[g][kk] = *(const bf16x8*)((const short*)Whh +
                          (size_t)(g * 512 + hcol) * 512 + ks + kk * 32 + lq * 8);

    float cp = 0.f;                              // c[brow][hcol] in-register

    for (int t = 0; t < T_; t++) {
        // ---- P (xW + bias): issue before the poll so it flies during it ----
        const float* Pr = P + (size_t)t * B_ * G4 + (size_t)brow * G4;
        float pv0 = Pr[0 * 512 + hcol];
        float pv1 = Pr[1 * 512 + hcol];
        float pv2 = Pr[2 * 512 + hcol];
        float pv3 = Pr[3 * 512 + hcol];

        // ---- A fragments (h rows MI*16+lm, this wave's K-slice) ----
        bf16x8 a[4];
        if (t == 0) {
            const unsigned short* A = h0 + (size_t)(MI * 16 + lm) * 512 + ks;
            #pragma unroll
            for (int kk = 0; kk < 4; kk++)
                a[kk] = *(const bf16x8*)(A + kk * 32 + lq * 8);
        } else {
            // parallel poll: lanes 0..7 watch octet w's 8 producer flags
            if (lane < 8) {
                unsigned want = (unsigned)t;
                while (__hip_atomic_load(wFlg + lane * 32, __ATOMIC_RELAXED,
                                         __HIP_MEMORY_SCOPE_AGENT) < want)
                    __builtin_amdgcn_s_sleep(1);
            }
            __builtin_amdgcn_wave_barrier();
            asm volatile("" ::: "memory");
            const unsigned long long* A = (const unsigned long long*)
                (((t & 1) ? hx1 : hx0) + ((size_t)(MI * 16 + lm) * 512 + ks) / 2);
            #pragma unroll
            for (int kk = 0; kk < 4; kk++) {
                union { unsigned long long q[2]; bf16x8 v; } cv;
                cv.q[0] = __hip_atomic_load(A + kk * 8 + lq * 2,
                                            __ATOMIC_RELAXED, __HIP_MEMORY_SCOPE_AGENT);
                cv.q[1] = __hip_atomic_load(A + kk * 8 + lq * 2 + 1,
                                            __ATOMIC_RELAXED, __HIP_MEMORY_SCOPE_AGENT);
                a[kk] = cv.v;
            }
        }

        // ---- GEMM slice ----
        f32x4 acc[4] = {};
        #pragma unroll
        for (int kk = 0; kk < 4; kk++) {
            acc[0] = MFMA_16x16x32_BF16(a[kk], bw[0][kk], acc[0]);
            acc[1] = MFMA_16x16x32_BF16(a[kk], bw[1][kk], acc[1]);
            acc[2] = MFMA_16x16x32_BF16(a[kk], bw[2][kk], acc[2]);
            acc[3] = MFMA_16x16x32_BF16(a[kk], bw[3][kk], acc[3]);
        }

        #pragma unroll
        for (int g = 0; g < 4; g++)
            #pragma unroll
            for (int r = 0; r < 4; r++)
                part[g * 4 + r][w][lane] = acc[g][r];
        __syncthreads();

        // ---- reduce + cell (wave w handles row r==w) ----
        float gi = part[0*4+w][0][lane] + part[0*4+w][1][lane] + part[0*4+w][2][lane] + part[0*4+w][3][lane] + pv0;
        float gf = part[1*4+w][0][lane] + part[1*4+w][1][lane] + part[1*4+w][2][lane] + part[1*4+w][3][lane] + pv1;
        float gg = part[2*4+w][0][lane] + part[2*4+w][1][lane] + part[2*4+w][2][lane] + part[2*4+w][3][lane] + pv2;
        float go = part[3*4+w][0][lane] + part[3*4+w][1][lane] + part[3*4+w][2][lane] + part[3*4+w][3][lane] + pv3;
        float si = 1.f / (1.f + expf(-gi));
        float sf = 1.f / (1.f + expf(-gf));
        float so = 1.f / (1.f + expf(-go));
        float cn = sf * cp + si * tanhf(gg);
        float hn = so * tanhf(cn);
        cp = cn;
        unsigned short hb = f2bf(hn);

        if (t < T_ - 1) {
            // pair adjacent hcols into one uint, agent-scope store (coherent)
            unsigned up = ((unsigned)(unsigned short)__shfl_down((int)hb, 1) << 16) | (unsigned)hb;
            unsigned* HW = (t & 1) ? hx0 : hx1;  // step t writes; t+1 reads
            if (!(lm & 1))
                __hip_atomic_store(HW + (brow * 512 + hcol) / 2, up,
                                   __ATOMIC_RELAXED, __HIP_MEMORY_SCOPE_AGENT);
            // each wave drains ITS OWN h stores before the block signals
            asm volatile("s_waitcnt vmcnt(0)" ::: "memory");
            __syncthreads();
            if (threadIdx.x == 0)
                __hip_atomic_store(myFlg, (unsigned)(t + 1), __ATOMIC_RELAXED,
                                   __HIP_MEMORY_SCOPE_AGENT);
        }
        // Hall store OFF the critical path (consumed only after kernel end)
        Hall[(size_t)t * (B_ * H_) + brow * 512 + hcol] = hb;
    }
}

// ---------------------------------------------------------------------------
// Logits: Hall[3072,512](bf16) @ Wout_bf^T + b_out -> fp32 out[b][t+1][v].
// 256x256 tile (staged-traffic-optimal: total LDS-staged bytes 368->246 MB),
// 512 thr / 8 waves (wave = 128x64, acc[8][4]), BK=32, double-buffered
// global_load_lds, swizzled LDS. Grid 8*(5*12) = 480: each XCD owns 5
// B-panels (2.6 MB, L2-resident) and streams the 12 M-tiles (MI-major).
// ---------------------------------------------------------------------------
__global__ __launch_bounds__(512) void k_logits(const unsigned short* __restrict__ Hall,
                                                const unsigned short* __restrict__ Wout,
                                                const float* __restrict__ bout,
                                                float* __restrict__ out) {
    __shared__ unsigned short ldsA[2][8192];     // [buf][256*32] swizzled
    __shared__ unsigned short ldsB[2][8192];
    int bid = blockIdx.x;                        // 0..479
    int xcd = bid & 7;
    int q   = bid >> 3;                          // 0..59
    int MI  = q % 12;                            // M-tile (256 rows = 2 t)
    int NI  = xcd * 5 + q / 12;                  // 0..39 (panel resident/XCD)
    int i    = threadIdx.x;                      // 0..511
    int w = i >> 6, lane = i & 63;
    int lm = lane & 15, lq = lane >> 4;
    int wr = w >> 2, wc = w & 3;                 // 2 x 4 wave grid

    int mm0 = ((i >> 2) & 7) ^ ((i >> 4) & 1);   // writer inverse swizzle
    int li  = i ^ mm0;
    const unsigned short* gA = Hall + (size_t)(MI * 256 + (li >> 2)) * 512 + (li & 3) * 8;
    const unsigned short* gB = Wout + (size_t)(NI * 256 + (li >> 2)) * 512 + (li & 3) * 8;
    unsigned short* lA = &ldsA[0][0] + i * 8;
    unsigned short* lB = &ldsB[0][0] + i * 8;

    auto stage = [&](int buf, int ks) {
        int go = ks * 32;
        gl16(gA + go,             lA + buf * 8192);
        gl16(gA + go + 128 * 512, lA + buf * 8192 + 4096);
        gl16(gB + go,             lB + buf * 8192);
        gl16(gB + go + 128 * 512, lB + buf * 8192 + 4096);
    };

    f32x4 acc[8][4] = {};
    stage(0, 0);
    for (int ksi = 0; ksi < 16; ksi++) {
        int cur = ksi & 1;
        if (ksi < 15) stage(cur ^ 1, ksi + 1);
        __syncthreads();                         // staging of cur complete
        bf16x8 af[8], bfr[4];
        #pragma unroll
        for (int mi = 0; mi < 8; mi++)
            af[mi] = *(const bf16x8*)&ldsA[cur][swz16(wr * 128 + mi * 16 + lm, lq)];
        #pragma unroll
        for (int ni = 0; ni < 4; ni++)
            bfr[ni] = *(const bf16x8*)&ldsB[cur][swz16(wc * 64 + ni * 16 + lm, lq)];
        #pragma unroll
        for (int mi = 0; mi < 8; mi++)
            #pragma unroll
            for (int ni = 0; ni < 4; ni++)
                acc[mi][ni] = MFMA_16x16x32_BF16(af[mi], bfr[ni], acc[mi][ni]);
        __syncthreads();                         // done reading cur
    }

    float bias[4];
    #pragma unroll
    for (int ni = 0; ni < 4; ni++) {
        int n = NI * 256 + wc * 64 + ni * 16 + lm;
        bias[ni] = (n < V_) ? bout[n] : 0.f;
    }

    // epilogue: m = t*128 + b with t = m>>7
    #pragma unroll
    for (int mi = 0; mi < 8; mi++) {
        #pragma unroll
        for (int r = 0; r < 4; r++) {
            int m = MI * 256 + wr * 128 + mi * 16 + lq * 4 + r;
            int b = m & 127, t = m >> 7;
            float* orow = out + ((size_t)b * TP1 + t + 1) * V_;
            #pragma unroll
            for (int ni = 0; ni < 4; ni++) {
                int n = NI * 256 + wc * 64 + ni * 16 + lm;
                if (n < V_) orow[n] = acc[mi][ni][r] + bias[ni];
            }
        }
    }
}

// ---------------------------------------------------------------------------
extern "C" void kernel_launch(void* const* d_in, const int* in_sizes, int n_in,
                              void* d_out, int out_size, void* d_ws, size_t ws_size,
                              hipStream_t stream) {
    const float* images   = (const float*)d_in[0];
    const int*   captions = (const int*)d_in[1];
    const int*   cap_len  = (const int*)d_in[2];
    const float* Wemb     = (const float*)d_in[3];
    const float* Wih      = (const float*)d_in[4];
    const float* Whh      = (const float*)d_in[5];
    const float* bih      = (const float*)d_in[6];
    const float* bhh      = (const float*)d_in[7];
    const float* Wout     = (const float*)d_in[8];
    const float* bout     = (const float*)d_in[9];
    float* out = (float*)d_out;

    // workspace layout (all sizes multiples of 256B)
    char* ws = (char*)d_ws;
    unsigned short* Wih_bf  = (unsigned short*)(ws);              //  2,097,152
    unsigned short* Whh_bf  = (unsigned short*)(ws + 2097152);    //  2,097,152
    unsigned short* Wout_bf = (unsigned short*)(ws + 4194304);    // 10,485,760 (10240 rows)
    unsigned short* Xemb    = (unsigned short*)(ws + 14680064);   //  3,145,728
    unsigned short* Hall    = (unsigned short*)(ws + 17825792);   //  3,145,728
    unsigned short* h0      = (unsigned short*)(ws + 20971520);   //    131,072
    unsigned*       hx0     = (unsigned*)(ws + 21102592);         //    131,072
    unsigned*       hx1     = (unsigned*)(ws + 21233664);         //    131,072
    unsigned*       flg     = (unsigned*)(ws + 21364736);         //     32,768
    constexpr size_t P_OFF   = 21397504;
    constexpr size_t WS_NEED = P_OFF + 25165824;   // 46,563,328
    bool ws_ok = (ws_size >= WS_NEED);
    float* P = ws_ok ? (float*)(ws + P_OFF) : (float*)d_out;

    // ALL prep in one launch (staging + embed + start + flag reset)
    k_prep<<<9898, 256, 0, stream>>>(Wih, Whh, Wout, images, Wemb, captions,
                                     cap_len, Wih_bf, Whh_bf, Wout_bf, h0,
                                     Xemb, out, flg, ws_ok ? 1 : 0);

    // hoisted input GEMM: P = Xemb @ Wih^T + (bih + bhh)
    k_pregemm<<<384, 256, 0, stream>>>(Xemb, Wih_bf, bih, bhh, P);

    // whole recurrence in ONE persistent kernel (per-producer flags)
    k_lstm<<<256, 256, 0, stream>>>(P, h0, hx0, hx1, Hall, Whh_bf, flg);

    // fallback only: start rows after P-in-out was consumed
    if (!ws_ok) k_start<<<1250, 256, 0, stream>>>(out, cap_len);

    // logits: 256x256 tiles, panel-resident XCD swizzle
    k_logits<<<480, 512, 0, stream>>>(Hall, Wout_bf, bout, out);
}

// Round 10
// 319.203 us; speedup vs baseline: 1.0344x; 1.0344x over previous
//
#include <hip/hip_runtime.h>

// ---- problem constants ----
constexpr int B_  = 128;
constexpr int T_  = 24;
constexpr int E_  = 512;
constexpr int H_  = 512;
constexpr int V_  = 10000;
constexpr int G4  = 2048;   // 4*H
constexpr int TP1 = 25;     // T+1

typedef __attribute__((ext_vector_type(8))) short bf16x8;   // 8 bf16 = 4 VGPR
typedef __attribute__((ext_vector_type(4))) short short4v;  // 4 bf16 = 8 B
typedef __attribute__((ext_vector_type(4))) float f32x4;

#define MFMA_16x16x32_BF16(a, b, c) __builtin_amdgcn_mfma_f32_16x16x32_bf16((a), (b), (c), 0, 0, 0)

// fp32 -> bf16 round-to-nearest-even (bit-level, no header ABI dependence)
__device__ inline unsigned short f2bf(float f) {
    unsigned int u = __float_as_uint(f);
    unsigned int r = (u + 0x7FFFu + ((u >> 16) & 1u)) >> 16;
    return (unsigned short)r;
}

// async global->LDS, 16B per lane. LDS dest must be linear-in-lane.
__device__ inline void gl16(const unsigned short* g, unsigned short* l) {
    __builtin_amdgcn_global_load_lds(
        (const __attribute__((address_space(1))) unsigned int*)g,
        (__attribute__((address_space(3))) unsigned int*)l, 16, 0, 0);
}

// LDS granule swizzle for [R][32] bf16 tiles (kept from R5 — harmless).
__device__ inline int swz16(int row, int lq) {      // returns short offset
    return (((row << 2) | lq) ^ (row & 7)) << 3;
}

// ---------------------------------------------------------------------------
// ALL prep in ONE launch: fp32->bf16 weight staging, embedding gather,
// t=0 one-hot row + length tail, per-producer flag reset.
// ---------------------------------------------------------------------------
__global__ __launch_bounds__(256) void k_prep(const float* __restrict__ Wih,
                                              const float* __restrict__ Whh,
                                              const float* __restrict__ Wout,
                                              const float* __restrict__ images,
                                              const float* __restrict__ Wemb,
                                              const int* __restrict__ captions,
                                              const int* __restrict__ cap_len,
                                              unsigned short* __restrict__ dWih,
                                              unsigned short* __restrict__ dWhh,
                                              unsigned short* __restrict__ dWout,
                                              unsigned short* __restrict__ dimg,
                                              unsigned short* __restrict__ Xemb,
                                              float* __restrict__ out,
                                              unsigned* __restrict__ flg) {
    int b = blockIdx.x;
    if (b == 0) flg[threadIdx.x * 32] = 0u;      // 256 producer flags
    if (b < 7112) {                              // fp32 -> bf16 segments
        const float* src; unsigned short* dst; int i;
        if (b < 1024)      { src = Wih;    dst = dWih;  i = b * 256 + threadIdx.x; }
        else if (b < 2048) { src = Whh;    dst = dWhh;  i = (b - 1024) * 256 + threadIdx.x; }
        else if (b < 7048) { src = Wout;   dst = dWout; i = (b - 2048) * 256 + threadIdx.x; }
        else               { src = images; dst = dimg;  i = (b - 7048) * 256 + threadIdx.x; }
        float4 v = ((const float4*)src)[i];
        short4v o;
        o[0] = (short)f2bf(v.x); o[1] = (short)f2bf(v.y);
        o[2] = (short)f2bf(v.z); o[3] = (short)f2bf(v.w);
        ((short4v*)dst)[i] = o;
    } else if (b < 8648) {                       // embedding gather
        int i = (b - 7112) * 256 + threadIdx.x;  // < 393216
        int row = i >> 7;                        // m = t*128 + bb
        int k4  = i & 127;
        int bb = row & 127, t = row >> 7;
        int tok = captions[bb * T_ + t];
        short4v o = {0, 0, 0, 0};
        if (tok > 0 && tok < V_) {               // tok==0 is padding -> zeros
            float4 v = ((const float4*)(Wemb + (long)tok * E_))[k4];
            o[0] = (short)f2bf(v.x); o[1] = (short)f2bf(v.y);
            o[2] = (short)f2bf(v.z); o[3] = (short)f2bf(v.w);
        }
        ((short4v*)Xemb)[(long)row * 128 + k4] = o;
    } else {                                     // t=0 one-hot row + tail
        int idx = (b - 8648) * 256 + threadIdx.x;
        constexpr int Q = V_ / 4;                // 2500 float4 per row
        if (idx < B_ * Q) {
            int bb = idx / Q;
            int q = idx - bb * Q;
            float4 zero = {0.f, 0.f, 0.f, 0.f};
            float4 one1 = {0.f, 1.f, 0.f, 0.f};  // one-hot at v=1
            ((float4*)out)[(long)bb * (TP1 * Q) + q] = (q == 0) ? one1 : zero;
        }
        if (idx < B_)
            out[(size_t)B_ * TP1 * V_ + idx] = (float)(cap_len[idx] - 1);
    }
}

// ---------------------------------------------------------------------------
// Persistent LSTM recurrence, per-producer flags, pregemm FUSED.
// gates = [x_t; h_{t-1}] @ [Wih; Whh]^T + bias : concatenated K=1024.
// Wave w owns K-slice [w*128,+128) of BOTH halves; Wih AND Whh fragments
// live in registers all 24 steps (128 VGPR). The x-part MFMAs have no
// cross-block dependency, so they issue BEFORE the flag poll and fill the
// poll idle window. No P buffer, no pregemm kernel.
// Sync protocol unchanged from R8/R9 (numerically verified): per-producer
// flags, agent-scope relaxed atomics for h, vmcnt(0) self-drain.
// ---------------------------------------------------------------------------
__global__ __launch_bounds__(256, 1) void k_lstm(const unsigned short* __restrict__ Xemb,
                                                 const unsigned short* __restrict__ h0,
                                                 unsigned* __restrict__ hx0,
                                                 unsigned* __restrict__ hx1,
                                                 unsigned short* __restrict__ Hall,
                                                 const unsigned short* __restrict__ Whh,
                                                 const unsigned short* __restrict__ Wih,
                                                 const float* __restrict__ bih,
                                                 const float* __restrict__ bhh,
                                                 unsigned* __restrict__ flg) {
    __shared__ float part[16][4][64];            // [g*4+r][wave][lane]
    int w    = threadIdx.x >> 6;                 // 0..3 (K-slice / cell row)
    int lane = threadIdx.x & 63;
    int lm = lane & 15, lq = lane >> 4;
    int MI = blockIdx.x >> 5;                    // 0..7
    int HG = blockIdx.x & 31;                    // 0..31
    int hcol = HG * 16 + lm;
    int ks = w * 128;
    int brow = MI * 16 + lq * 4 + w;             // this lane's cell row (b)
    unsigned* myFlg = flg + (MI * 32 + HG) * 32;          // producer flag
    unsigned* wFlg  = flg + (MI * 32 + (w << 3)) * 32;    // octet-w flag base

    // resident weight fragments (bf16), reused all 24 steps
    bf16x8 bw[4][4];                             // Whh [gate][kk]
    bf16x8 wv[4][4];                             // Wih [gate][kk]
    #pragma unroll
    for (int g = 0; g < 4; g++)
        #pragma unroll
        for (int kk = 0; kk < 4; kk++) {
            size_t off = (size_t)(g * 512 + hcol) * 512 + ks + kk * 32 + lq * 8;
            bw[g][kk] = *(const bf16x8*)((const short*)Whh + off);
            wv[g][kk] = *(const bf16x8*)((const short*)Wih + off);
        }

    // bias for this lane's cell outputs (row r==w, col hcol)
    float bs0 = bih[0 * 512 + hcol] + bhh[0 * 512 + hcol];
    float bs1 = bih[1 * 512 + hcol] + bhh[1 * 512 + hcol];
    float bs2 = bih[2 * 512 + hcol] + bhh[2 * 512 + hcol];
    float bs3 = bih[3 * 512 + hcol] + bhh[3 * 512 + hcol];

    float cp = 0.f;                              // c[brow][hcol] in-register

    for (int t = 0; t < T_; t++) {
        // ---- x-part: no cross-block dependency; runs during producers' work
        const unsigned short* X = Xemb + ((size_t)(t * 128 + MI * 16 + lm)) * 512 + ks;
        bf16x8 xa[4];
        #pragma unroll
        for (int kk = 0; kk < 4; kk++)
            xa[kk] = *(const bf16x8*)(X + kk * 32 + lq * 8);

        f32x4 acc[4] = {};
        #pragma unroll
        for (int kk = 0; kk < 4; kk++) {
            acc[0] = MFMA_16x16x32_BF16(xa[kk], wv[0][kk], acc[0]);
            acc[1] = MFMA_16x16x32_BF16(xa[kk], wv[1][kk], acc[1]);
            acc[2] = MFMA_16x16x32_BF16(xa[kk], wv[2][kk], acc[2]);
            acc[3] = MFMA_16x16x32_BF16(xa[kk], wv[3][kk], acc[3]);
        }

        // ---- h fragments (wait for producers, then load) ----
        bf16x8 a[4];
        if (t == 0) {
            const unsigned short* A = h0 + (size_t)(MI * 16 + lm) * 512 + ks;
            #pragma unroll
            for (int kk = 0; kk < 4; kk++)
                a[kk] = *(const bf16x8*)(A + kk * 32 + lq * 8);
        } else {
            // parallel poll: lanes 0..7 watch octet w's 8 producer flags
            if (lane < 8) {
                unsigned want = (unsigned)t;
                while (__hip_atomic_load(wFlg + lane * 32, __ATOMIC_RELAXED,
                                         __HIP_MEMORY_SCOPE_AGENT) < want)
                    __builtin_amdgcn_s_sleep(1);
            }
            __builtin_amdgcn_wave_barrier();
            asm volatile("" ::: "memory");
            const unsigned long long* A = (const unsigned long long*)
                (((t & 1) ? hx1 : hx0) + ((size_t)(MI * 16 + lm) * 512 + ks) / 2);
            #pragma unroll
            for (int kk = 0; kk < 4; kk++) {
                union { unsigned long long q[2]; bf16x8 v; } cv;
                cv.q[0] = __hip_atomic_load(A + kk * 8 + lq * 2,
                                            __ATOMIC_RELAXED, __HIP_MEMORY_SCOPE_AGENT);
                cv.q[1] = __hip_atomic_load(A + kk * 8 + lq * 2 + 1,
                                            __ATOMIC_RELAXED, __HIP_MEMORY_SCOPE_AGENT);
                a[kk] = cv.v;
            }
        }

        // ---- h-part GEMM slice ----
        #pragma unroll
        for (int kk = 0; kk < 4; kk++) {
            acc[0] = MFMA_16x16x32_BF16(a[kk], bw[0][kk], acc[0]);
            acc[1] = MFMA_16x16x32_BF16(a[kk], bw[1][kk], acc[1]);
            acc[2] = MFMA_16x16x32_BF16(a[kk], bw[2][kk], acc[2]);
            acc[3] = MFMA_16x16x32_BF16(a[kk], bw[3][kk], acc[3]);
        }

        #pragma unroll
        for (int g = 0; g < 4; g++)
            #pragma unroll
            for (int r = 0; r < 4; r++)
                part[g * 4 + r][w][lane] = acc[g][r];
        __syncthreads();

        // ---- reduce + cell (wave w handles row r==w) ----
        float gi = part[0*4+w][0][lane] + part[0*4+w][1][lane] + part[0*4+w][2][lane] + part[0*4+w][3][lane] + bs0;
        float gf = part[1*4+w][0][lane] + part[1*4+w][1][lane] + part[1*4+w][2][lane] + part[1*4+w][3][lane] + bs1;
        float gg = part[2*4+w][0][lane] + part[2*4+w][1][lane] + part[2*4+w][2][lane] + part[2*4+w][3][lane] + bs2;
        float go = part[3*4+w][0][lane] + part[3*4+w][1][lane] + part[3*4+w][2][lane] + part[3*4+w][3][lane] + bs3;
        float si = 1.f / (1.f + expf(-gi));
        float sf = 1.f / (1.f + expf(-gf));
        float so = 1.f / (1.f + expf(-go));
        float cn = sf * cp + si * tanhf(gg);
        float hn = so * tanhf(cn);
        cp = cn;
        unsigned short hb = f2bf(hn);

        if (t < T_ - 1) {
            // pair adjacent hcols into one uint, agent-scope store (coherent)
            unsigned up = ((unsigned)(unsigned short)__shfl_down((int)hb, 1) << 16) | (unsigned)hb;
            unsigned* HW = (t & 1) ? hx0 : hx1;  // step t writes; t+1 reads
            if (!(lm & 1))
                __hip_atomic_store(HW + (brow * 512 + hcol) / 2, up,
                                   __ATOMIC_RELAXED, __HIP_MEMORY_SCOPE_AGENT);
            // each wave drains ITS OWN h stores before the block signals
            asm volatile("s_waitcnt vmcnt(0)" ::: "memory");
            __syncthreads();
            if (threadIdx.x == 0)
                __hip_atomic_store(myFlg, (unsigned)(t + 1), __ATOMIC_RELAXED,
                                   __HIP_MEMORY_SCOPE_AGENT);
        }
        // Hall store OFF the critical path (consumed only after kernel end)
        Hall[(size_t)t * (B_ * H_) + brow * 512 + hcol] = hb;
    }
}

// ---------------------------------------------------------------------------
// Logits: Hall[3072,512](bf16) @ Wout_bf^T + b_out -> fp32 out[b][t+1][v].
// REVERTED to the R5 128x128 structure (best measured: 77 us). 1896 blocks,
// 32 KB LDS -> 4 blocks/CU co-resident; that concurrency, not staged-byte
// count, is what the R8/R9 experiments showed matters.
// ---------------------------------------------------------------------------
__global__ __launch_bounds__(256) void k_logits(const unsigned short* __restrict__ Hall,
                                                const unsigned short* __restrict__ Wout,
                                                const float* __restrict__ bout,
                                                float* __restrict__ out) {
    __shared__ unsigned short ldsA[2][4096];     // [buf][128*32] swizzled
    __shared__ unsigned short ldsB[2][4096];
    int bid = blockIdx.x;
    int xcd = bid & 7;
    int q   = bid >> 3;                          // 0..236
    int MI  = xcd * 3 + (q % 3);                 // 0..23 (== timestep t)
    int NI  = q / 3;                             // 0..78
    int i    = threadIdx.x;
    int w = i >> 6, lane = i & 63;
    int lm = lane & 15, lq = lane >> 4;
    int wr = w >> 1, wc = w & 1;

    int mm0 = ((i >> 2) & 7) ^ ((i >> 4) & 1);   // writer inverse swizzle
    int li  = i ^ mm0;
    const unsigned short* gA = Hall + (size_t)(MI * 128 + (li >> 2)) * 512 + (li & 3) * 8;
    const unsigned short* gB = Wout + (size_t)(NI * 128 + (li >> 2)) * 512 + (li & 3) * 8;
    unsigned short* lA = &ldsA[0][0] + i * 8;
    unsigned short* lB = &ldsB[0][0] + i * 8;

    auto stage = [&](int buf, int ks) {
        int go = ks * 32;
        gl16(gA + go,            lA + buf * 4096);
        gl16(gA + go + 64 * 512, lA + buf * 4096 + 2048);
        gl16(gB + go,            lB + buf * 4096);
        gl16(gB + go + 64 * 512, lB + buf * 4096 + 2048);
    };

    f32x4 acc[4][4] = {};
    stage(0, 0);
    for (int ksi = 0; ksi < 16; ksi++) {
        int cur = ksi & 1;
        if (ksi < 15) stage(cur ^ 1, ksi + 1);
        __syncthreads();                         // staging of cur complete
        bf16x8 af[4], bfr[4];
        #pragma unroll
        for (int mi = 0; mi < 4; mi++)
            af[mi] = *(const bf16x8*)&ldsA[cur][swz16(wr * 64 + mi * 16 + lm, lq)];
        #pragma unroll
        for (int ni = 0; ni < 4; ni++)
            bfr[ni] = *(const bf16x8*)&ldsB[cur][swz16(wc * 64 + ni * 16 + lm, lq)];
        #pragma unroll
        for (int mi = 0; mi < 4; mi++)
            #pragma unroll
            for (int ni = 0; ni < 4; ni++)
                acc[mi][ni] = MFMA_16x16x32_BF16(af[mi], bfr[ni], acc[mi][ni]);
        __syncthreads();                         // done reading cur
    }

    // epilogue: rows of this M-tile are exactly (t = MI, b = 0..127)
    #pragma unroll
    for (int mi = 0; mi < 4; mi++) {
        #pragma unroll
        for (int r = 0; r < 4; r++) {
            int b = wr * 64 + mi * 16 + lq * 4 + r;
            float* orow = out + ((size_t)b * TP1 + MI + 1) * V_;
            #pragma unroll
            for (int ni = 0; ni < 4; ni++) {
                int n = NI * 128 + wc * 64 + ni * 16 + lm;
                if (n < V_) orow[n] = acc[mi][ni][r] + bout[n];
            }
        }
    }
}

// ---------------------------------------------------------------------------
extern "C" void kernel_launch(void* const* d_in, const int* in_sizes, int n_in,
                              void* d_out, int out_size, void* d_ws, size_t ws_size,
                              hipStream_t stream) {
    const float* images   = (const float*)d_in[0];
    const int*   captions = (const int*)d_in[1];
    const int*   cap_len  = (const int*)d_in[2];
    const float* Wemb     = (const float*)d_in[3];
    const float* Wih      = (const float*)d_in[4];
    const float* Whh      = (const float*)d_in[5];
    const float* bih      = (const float*)d_in[6];
    const float* bhh      = (const float*)d_in[7];
    const float* Wout     = (const float*)d_in[8];
    const float* bout     = (const float*)d_in[9];
    float* out = (float*)d_out;

    // workspace layout (all sizes multiples of 256B) — P eliminated
    char* ws = (char*)d_ws;
    unsigned short* Wih_bf  = (unsigned short*)(ws);              //  2,097,152
    unsigned short* Whh_bf  = (unsigned short*)(ws + 2097152);    //  2,097,152
    unsigned short* Wout_bf = (unsigned short*)(ws + 4194304);    // 10,240,000
    unsigned short* Xemb    = (unsigned short*)(ws + 14434304);   //  3,145,728
    unsigned short* Hall    = (unsigned short*)(ws + 17580032);   //  3,145,728
    unsigned short* h0      = (unsigned short*)(ws + 20725760);   //    131,072
    unsigned*       hx0     = (unsigned*)(ws + 20856832);         //    131,072
    unsigned*       hx1     = (unsigned*)(ws + 20987904);         //    131,072
    unsigned*       flg     = (unsigned*)(ws + 21118976);         //     32,768

    // ALL prep in one launch (staging + embed + start + flag reset)
    k_prep<<<9898, 256, 0, stream>>>(Wih, Whh, Wout, images, Wemb, captions,
                                     cap_len, Wih_bf, Whh_bf, Wout_bf, h0,
                                     Xemb, out, flg);

    // whole recurrence (input GEMM fused, K=1024) in ONE persistent kernel
    k_lstm<<<256, 256, 0, stream>>>(Xemb, h0, hx0, hx1, Hall, Whh_bf, Wih_bf,
                                    bih, bhh, flg);

    // logits: 128x128 tiles (best measured structure)
    k_logits<<<1896, 256, 0, stream>>>(Hall, Wout_bf, bout, out);
}